// Round 1
// baseline (2237.636 us; speedup 1.0000x reference)
//
#include <hip/hip_runtime.h>

#define NN 50000
#define NE 800000
#define SLOPE 0.2f

// monotonic float<->uint encoding for atomicMax on signed floats
__device__ __forceinline__ unsigned int f2u(float f) {
    unsigned int b = __float_as_uint(f);
    return (b & 0x80000000u) ? ~b : (b | 0x80000000u);
}
__device__ __forceinline__ float u2f(unsigned int u) {
    return __uint_as_float((u & 0x80000000u) ? (u & 0x7fffffffu) : ~u);
}
__device__ __forceinline__ float lrelu(float v) { return v >= 0.f ? v : SLOPE * v; }

// h = X @ W  (N x 128 * 128 x 128), fused per-node attention coefficients
__global__ __launch_bounds__(256) void gemm_attn(
    const float* __restrict__ X, const float* __restrict__ W,
    const float* __restrict__ a_src, const float* __restrict__ a_dst,
    float* __restrict__ Hout, float* __restrict__ asrc, float* __restrict__ adst)
{
    __shared__ float Ws[128][128];   // 64 KB
    __shared__ float xs[2][128];
    const int tx = threadIdx.x;      // col 0..127
    const int ty = threadIdx.y;      // 0..1
    const int tid = ty * 128 + tx;
    for (int i = tid; i < 128 * 128; i += 256) Ws[i >> 7][i & 127] = W[i];
    const float cs = a_src[tx], cd = a_dst[tx];
    __syncthreads();
    const int rowBase = blockIdx.x * 32;
    for (int it = 0; it < 16; ++it) {
        const int row = rowBase + it * 2 + ty;
        __syncthreads();
        if (row < NN) xs[ty][tx] = X[row * 128 + tx];
        __syncthreads();
        if (row < NN) {
            float sum = 0.f;
            #pragma unroll
            for (int k = 0; k < 128; ++k) sum = fmaf(xs[ty][k], Ws[k][tx], sum);
            Hout[row * 128 + tx] = sum;
            float s1 = sum * cs, s2 = sum * cd;
            #pragma unroll
            for (int m = 8; m >= 1; m >>= 1) {
                s1 += __shfl_xor(s1, m, 16);
                s2 += __shfl_xor(s2, m, 16);
            }
            if ((tx & 15) == 0) {
                asrc[row * 8 + (tx >> 4)] = s1;
                adst[row * 8 + (tx >> 4)] = s2;
            }
        }
    }
}

__global__ __launch_bounds__(256) void init_nh(unsigned int* __restrict__ emax,
                                               float* __restrict__ denom) {
    int i = blockIdx.x * 256 + threadIdx.x;
    if (i < NN * 8) { emax[i] = 0x007fffffu; /* encoded -inf */ denom[i] = 0.f; }
}

__global__ __launch_bounds__(256) void init_bias(float* __restrict__ out,
                                                 const float* __restrict__ bias) {
    int i = blockIdx.x * 256 + threadIdx.x;
    if (i < NN * 128) out[i] = bias[i & 127];
}

__global__ __launch_bounds__(256) void edge_max(
    const int* __restrict__ src, const int* __restrict__ dst,
    const float* __restrict__ asrc, const float* __restrict__ adst,
    unsigned int* __restrict__ emax)
{
    int e = blockIdx.x * 256 + threadIdx.x;
    if (e >= NE) return;
    int s = src[e], d = dst[e];
    if ((unsigned)s >= NN) s = 0;
    if ((unsigned)d >= NN) d = 0;
    #pragma unroll
    for (int h = 0; h < 8; ++h) {
        float v = lrelu(asrc[s * 8 + h] + adst[d * 8 + h]);
        atomicMax(&emax[d * 8 + h], f2u(v));
    }
}

__global__ __launch_bounds__(256) void edge_exp(
    const int* __restrict__ src, const int* __restrict__ dst,
    const float* __restrict__ asrc, const float* __restrict__ adst,
    const unsigned int* __restrict__ emax,
    float* __restrict__ denom, float* __restrict__ exbuf)
{
    int e = blockIdx.x * 256 + threadIdx.x;
    if (e >= NE) return;
    int s = src[e], d = dst[e];
    if ((unsigned)s >= NN) s = 0;
    if ((unsigned)d >= NN) d = 0;
    #pragma unroll
    for (int h = 0; h < 8; ++h) {
        float v = lrelu(asrc[s * 8 + h] + adst[d * 8 + h]);
        float m = u2f(emax[d * 8 + h]);
        float ex = expf(v - m);
        exbuf[e * 8 + h] = ex;           // stash unnormalized exp in alpha slot
        atomicAdd(&denom[d * 8 + h], ex);
    }
}

// one thread per (edge, channel); also finalizes alpha (lane c%16==0)
__global__ __launch_bounds__(256) void edge_aggr(
    const int* __restrict__ src, const int* __restrict__ dst,
    const float* __restrict__ Hfeat, const float* __restrict__ denom,
    float* __restrict__ alpha, float* __restrict__ out)
{
    int gid = blockIdx.x * 256 + threadIdx.x;   // NE*128 = 102.4M < 2^31
    int e = gid >> 7;
    if (e >= NE) return;
    int c = gid & 127;
    int s = src[e], d = dst[e];
    if ((unsigned)s >= NN) s = 0;
    if ((unsigned)d >= NN) d = 0;
    int h = c >> 4;
    float ex = alpha[e * 8 + h];
    float a = ex / (denom[d * 8 + h] + 1e-16f);
    if ((c & 15) == 0) alpha[e * 8 + h] = a;    // same-wave read-then-write only
    atomicAdd(&out[d * 128 + c], Hfeat[s * 128 + c] * a);
}

extern "C" void kernel_launch(void* const* d_in, const int* in_sizes, int n_in,
                              void* d_out, int out_size, void* d_ws, size_t ws_size,
                              hipStream_t stream)
{
    const float* x   = (const float*)d_in[0];
    const float* W1  = (const float*)d_in[1];
    const float* as1 = (const float*)d_in[2];
    const float* ad1 = (const float*)d_in[3];
    const float* b1  = (const float*)d_in[4];
    const float* W2  = (const float*)d_in[5];
    const float* as2 = (const float*)d_in[6];
    const float* ad2 = (const float*)d_in[7];
    const float* b2  = (const float*)d_in[8];
    const int*   ei  = (const int*)d_in[9];
    const int* srcp = ei;
    const int* dstp = ei + NE;

    float* outx   = (float*)d_out;            // [NN*128]
    float* alpha1 = outx + (size_t)NN * 128;  // [NE*8]
    float* alpha2 = alpha1 + (size_t)NE * 8;  // [NE*8]

    float* ws    = (float*)d_ws;
    float* hbuf  = ws;                          // NN*128
    float* x1    = hbuf + (size_t)NN * 128;     // NN*128
    float* asrc  = x1 + (size_t)NN * 128;       // NN*8
    float* adst  = asrc + (size_t)NN * 8;       // NN*8
    unsigned int* emax = (unsigned int*)(adst + (size_t)NN * 8);  // NN*8
    float* denom = (float*)emax + (size_t)NN * 8;                 // NN*8

    dim3 gB(128, 2);
    int gemmGrid = (NN + 31) / 32;
    int nhGrid   = (NN * 8 + 255) / 256;
    int edgeGrid = (NE + 255) / 256;
    int aggrGrid = (NE * 128) / 256;
    int biasGrid = (NN * 128 + 255) / 256;

    // ---- layer 1 ----
    gemm_attn<<<gemmGrid, gB, 0, stream>>>(x, W1, as1, ad1, hbuf, asrc, adst);
    init_nh<<<nhGrid, 256, 0, stream>>>(emax, denom);
    edge_max<<<edgeGrid, 256, 0, stream>>>(srcp, dstp, asrc, adst, emax);
    edge_exp<<<edgeGrid, 256, 0, stream>>>(srcp, dstp, asrc, adst, emax, denom, alpha1);
    init_bias<<<biasGrid, 256, 0, stream>>>(x1, b1);
    edge_aggr<<<aggrGrid, 256, 0, stream>>>(srcp, dstp, hbuf, denom, alpha1, x1);

    // ---- layer 2 ----
    gemm_attn<<<gemmGrid, gB, 0, stream>>>(x1, W2, as2, ad2, hbuf, asrc, adst);
    init_nh<<<nhGrid, 256, 0, stream>>>(emax, denom);
    edge_max<<<edgeGrid, 256, 0, stream>>>(srcp, dstp, asrc, adst, emax);
    edge_exp<<<edgeGrid, 256, 0, stream>>>(srcp, dstp, asrc, adst, emax, denom, alpha2);
    init_bias<<<biasGrid, 256, 0, stream>>>(outx, b2);
    edge_aggr<<<aggrGrid, 256, 0, stream>>>(srcp, dstp, hbuf, denom, alpha2, outx);
}

// Round 2
// 612.828 us; speedup vs baseline: 3.6513x; 3.6513x over previous
//
#include <hip/hip_runtime.h>

#define NN 50000
#define NE 800000
#define SLOPE 0.2f
#define NEG_INF (-1e30f)

__device__ __forceinline__ float lrelu(float v) { return v >= 0.f ? v : SLOPE * v; }

// ---------------- GEMM + fused attention coefficients ----------------
__global__ __launch_bounds__(256) void gemm_attn(
    const float* __restrict__ X, const float* __restrict__ W,
    const float* __restrict__ a_src, const float* __restrict__ a_dst,
    float* __restrict__ Hout, float* __restrict__ asrc, float* __restrict__ adst)
{
    __shared__ float Ws[128][128];   // 64 KB
    __shared__ float xs[2][128];
    const int tx = threadIdx.x;      // col 0..127
    const int ty = threadIdx.y;      // 0..1
    const int tid = ty * 128 + tx;
    for (int i = tid; i < 128 * 128; i += 256) Ws[i >> 7][i & 127] = W[i];
    const float cs = a_src[tx], cd = a_dst[tx];
    __syncthreads();
    const int rowBase = blockIdx.x * 32;
    for (int it = 0; it < 16; ++it) {
        const int row = rowBase + it * 2 + ty;
        __syncthreads();
        if (row < NN) xs[ty][tx] = X[row * 128 + tx];
        __syncthreads();
        if (row < NN) {
            float sum = 0.f;
            #pragma unroll
            for (int k = 0; k < 128; ++k) sum = fmaf(xs[ty][k], Ws[k][tx], sum);
            Hout[row * 128 + tx] = sum;
            float s1 = sum * cs, s2 = sum * cd;
            #pragma unroll
            for (int m = 8; m >= 1; m >>= 1) {
                s1 += __shfl_xor(s1, m, 16);
                s2 += __shfl_xor(s2, m, 16);
            }
            if ((tx & 15) == 0) {
                asrc[row * 8 + (tx >> 4)] = s1;
                adst[row * 8 + (tx >> 4)] = s2;
            }
        }
    }
}

// ---------------- CSR build (edge index identical for both layers) ----------------
__global__ __launch_bounds__(256) void zero_counts(int* __restrict__ counts) {
    int i = blockIdx.x * 256 + threadIdx.x;
    if (i < NN) counts[i] = 0;
}

__global__ __launch_bounds__(256) void hist_dst(const int* __restrict__ dst,
                                                int* __restrict__ counts) {
    int e = blockIdx.x * 256 + threadIdx.x;
    if (e >= NE) return;
    int d = dst[e];
    if ((unsigned)d >= NN) d = 0;
    atomicAdd(&counts[d], 1);
}

// single-block exclusive scan over NN counts -> off[NN+1], cursor copy
__global__ __launch_bounds__(1024) void scan_counts(const int* __restrict__ counts,
                                                    int* __restrict__ off,
                                                    int* __restrict__ cursor) {
    __shared__ int part[1024];
    const int T = 1024;
    const int chunk = (NN + T - 1) / T;   // 49
    int t = threadIdx.x;
    int beg = t * chunk, end = min(beg + chunk, NN);
    int s = 0;
    for (int i = beg; i < end; ++i) s += counts[i];
    part[t] = s;
    __syncthreads();
    for (int d = 1; d < T; d <<= 1) {
        int v = (t >= d) ? part[t - d] : 0;
        __syncthreads();
        part[t] += v;
        __syncthreads();
    }
    int run = (t == 0) ? 0 : part[t - 1];
    for (int i = beg; i < end; ++i) {
        off[i] = run;
        cursor[i] = run;
        run += counts[i];
    }
    if (t == T - 1) off[NN] = run;
}

__global__ __launch_bounds__(256) void scatter_csr(
    const int* __restrict__ src, const int* __restrict__ dst,
    int* __restrict__ cursor, int* __restrict__ csrE, int* __restrict__ csrS) {
    int e = blockIdx.x * 256 + threadIdx.x;
    if (e >= NE) return;
    int s = src[e], d = dst[e];
    if ((unsigned)s >= NN) s = 0;
    if ((unsigned)d >= NN) d = 0;
    int pos = atomicAdd(&cursor[d], 1);
    csrE[pos] = e;
    csrS[pos] = s;
}

// ---------------- fused per-node softmax + aggregate (one wave per node) ----------------
__global__ __launch_bounds__(256) void node_fused(
    const int* __restrict__ off, const int* __restrict__ csrE, const int* __restrict__ csrS,
    const float* __restrict__ asrc, const float* __restrict__ adst,
    const float* __restrict__ H, const float* __restrict__ bias,
    float* __restrict__ alpha, float* __restrict__ out)
{
    int wid = (blockIdx.x * 256 + threadIdx.x) >> 6;   // global wave id = node
    if (wid >= NN) return;
    const int lane = threadIdx.x & 63;
    const int n = wid;
    const int p0 = off[n], p1 = off[n + 1];
    const int deg = p1 - p0;
    const int h = lane & 7;      // head (softmax phase)
    const int el = lane >> 3;    // edge-local slot 0..7
    const float ad = adst[n * 8 + h];

    // phase 1: online (max, sum) per lane over strided edge chunks
    float m = NEG_INF, l = 0.f;
    for (int base = 0; base < deg; base += 8) {
        int i = base + el;
        if (i < deg) {
            int s = csrS[p0 + i];
            float v = lrelu(asrc[s * 8 + h] + ad);
            float nm = fmaxf(m, v);
            l = l * __expf(m - nm) + __expf(v - nm);
            m = nm;
        }
    }
    // combine across the 8 edge-slot groups (lanes differing in bits 3..5)
    #pragma unroll
    for (int msk = 8; msk <= 32; msk <<= 1) {
        float m2 = __shfl_xor(m, msk);
        float l2 = __shfl_xor(l, msk);
        float nm = fmaxf(m, m2);
        l = l * __expf(m - nm) + l2 * __expf(m2 - nm);
        m = nm;
    }
    const float inv = 1.f / (l + 1e-16f);

    // phase 2: alpha write + gather-aggregate, chunks of 8 edges
    float2 acc = {0.f, 0.f};
    const int hc = lane >> 3;    // head of this lane's channel pair (channels 2*lane,2*lane+1)
    for (int base = 0; base < deg; base += 8) {
        int i = base + el;
        float a = 0.f;
        int s = 0;
        if (i < deg) {
            int p = p0 + i;
            int e = csrE[p];
            s = csrS[p];
            float v = lrelu(asrc[s * 8 + h] + ad);
            a = __expf(v - m) * inv;
            alpha[(size_t)e * 8 + h] = a;
        }
        int cnt = min(8, deg - base);
        for (int k = 0; k < cnt; ++k) {
            float ak = __shfl(a, k * 8 + hc);
            int sk = __shfl(s, k * 8);
            const float2 hv = *(const float2*)&H[(size_t)sk * 128 + lane * 2];
            acc.x = fmaf(hv.x, ak, acc.x);
            acc.y = fmaf(hv.y, ak, acc.y);
        }
    }
    float2 o;
    o.x = acc.x + bias[lane * 2];
    o.y = acc.y + bias[lane * 2 + 1];
    *(float2*)&out[(size_t)n * 128 + lane * 2] = o;
}

extern "C" void kernel_launch(void* const* d_in, const int* in_sizes, int n_in,
                              void* d_out, int out_size, void* d_ws, size_t ws_size,
                              hipStream_t stream)
{
    const float* x   = (const float*)d_in[0];
    const float* W1  = (const float*)d_in[1];
    const float* as1 = (const float*)d_in[2];
    const float* ad1 = (const float*)d_in[3];
    const float* b1  = (const float*)d_in[4];
    const float* W2  = (const float*)d_in[5];
    const float* as2 = (const float*)d_in[6];
    const float* ad2 = (const float*)d_in[7];
    const float* b2  = (const float*)d_in[8];
    const int*   ei  = (const int*)d_in[9];
    const int* srcp = ei;
    const int* dstp = ei + NE;

    float* outx   = (float*)d_out;            // [NN*128]
    float* alpha1 = outx + (size_t)NN * 128;  // [NE*8]
    float* alpha2 = alpha1 + (size_t)NE * 8;  // [NE*8]

    float* ws   = (float*)d_ws;
    float* hbuf = ws;                          // NN*128
    float* x1   = hbuf + (size_t)NN * 128;     // NN*128
    float* asrc = x1 + (size_t)NN * 128;       // NN*8
    float* adst = asrc + (size_t)NN * 8;       // NN*8
    int* counts = (int*)(adst + (size_t)NN * 8);   // NN
    int* off    = counts + NN;                      // NN+1
    int* cursor = off + NN + 1;                     // NN
    int* csrE   = cursor + NN;                      // NE
    int* csrS   = csrE + NE;                        // NE

    dim3 gB(128, 2);
    int gemmGrid = (NN + 31) / 32;
    int nodeGrid = (NN + 3) / 4;           // 4 waves (nodes) per 256-thread block
    int edgeGrid = (NE + 255) / 256;
    int cntGrid  = (NN + 255) / 256;

    // ---- CSR build (shared by both layers) ----
    zero_counts<<<cntGrid, 256, 0, stream>>>(counts);
    hist_dst<<<edgeGrid, 256, 0, stream>>>(dstp, counts);
    scan_counts<<<1, 1024, 0, stream>>>(counts, off, cursor);
    scatter_csr<<<edgeGrid, 256, 0, stream>>>(srcp, dstp, cursor, csrE, csrS);

    // ---- layer 1 ----
    gemm_attn<<<gemmGrid, gB, 0, stream>>>(x, W1, as1, ad1, hbuf, asrc, adst);
    node_fused<<<nodeGrid, 256, 0, stream>>>(off, csrE, csrS, asrc, adst, hbuf, b1, alpha1, x1);

    // ---- layer 2 ----
    gemm_attn<<<gemmGrid, gB, 0, stream>>>(x1, W2, as2, ad2, hbuf, asrc, adst);
    node_fused<<<nodeGrid, 256, 0, stream>>>(off, csrE, csrS, asrc, adst, hbuf, b2, alpha2, outx);
}